// Round 4
// baseline (1458.863 us; speedup 1.0000x reference)
//
#include <hip/hip_runtime.h>

#define HD 64  // hidden == out dim

typedef __attribute__((ext_vector_type(8))) short bf16x8;
typedef __attribute__((ext_vector_type(4))) float f32x4;
typedef __attribute__((ext_vector_type(4))) unsigned short u16x4;

__device__ inline unsigned short f2bf(float x) {
  unsigned u = __float_as_uint(x);
  unsigned r = u + 0x7FFF + ((u >> 16) & 1);
  return (unsigned short)(r >> 16);
}
__device__ inline float bf2f(unsigned short h) {
  return __uint_as_float(((unsigned)h) << 16);
}

// ---------------- CSR build ----------------

__global__ void k_deg(const int* __restrict__ dst, int* __restrict__ deg, int E) {
  int e = blockIdx.x * blockDim.x + threadIdx.x;
  if (e < E) atomicAdd(&deg[dst[e]], 1);
}

// chunk = 1024 elements per block (256 threads x 4); also emits dinv = rsqrt(deg+1)
__global__ void k_scan1(const int* __restrict__ deg, int* __restrict__ row_start,
                        int* __restrict__ partials, float* __restrict__ dinv, int N) {
  __shared__ int sh[256];
  int t = threadIdx.x;
  int base = blockIdx.x * 1024 + t * 4;
  int v0 = 0, v1 = 0, v2 = 0, v3 = 0;
  if (base + 0 < N) v0 = deg[base + 0];
  if (base + 1 < N) v1 = deg[base + 1];
  if (base + 2 < N) v2 = deg[base + 2];
  if (base + 3 < N) v3 = deg[base + 3];
  if (base + 0 < N) dinv[base + 0] = rsqrtf((float)v0 + 1.0f);
  if (base + 1 < N) dinv[base + 1] = rsqrtf((float)v1 + 1.0f);
  if (base + 2 < N) dinv[base + 2] = rsqrtf((float)v2 + 1.0f);
  if (base + 3 < N) dinv[base + 3] = rsqrtf((float)v3 + 1.0f);
  int tsum = v0 + v1 + v2 + v3;
  sh[t] = tsum;
  __syncthreads();
  for (int off = 1; off < 256; off <<= 1) {
    int x = (t >= off) ? sh[t - off] : 0;
    __syncthreads();
    sh[t] += x;
    __syncthreads();
  }
  int excl = sh[t] - tsum;
  if (t == 255) partials[blockIdx.x] = sh[255];
  if (base + 0 < N) row_start[base + 0] = excl;
  if (base + 1 < N) row_start[base + 1] = excl + v0;
  if (base + 2 < N) row_start[base + 2] = excl + v0 + v1;
  if (base + 3 < N) row_start[base + 3] = excl + v0 + v1 + v2;
}

__global__ void k_scan2(int* partials, int nb) {  // nb <= 256
  __shared__ int sh[256];
  int t = threadIdx.x;
  int v = (t < nb) ? partials[t] : 0;
  sh[t] = v;
  __syncthreads();
  for (int off = 1; off < 256; off <<= 1) {
    int x = (t >= off) ? sh[t - off] : 0;
    __syncthreads();
    sh[t] += x;
    __syncthreads();
  }
  if (t < nb) partials[t] = sh[t] - v;  // exclusive
}

__global__ void k_scan3(int* __restrict__ row_start, const int* __restrict__ partials,
                        int N, int E) {
  int i = blockIdx.x * blockDim.x + threadIdx.x;
  if (i < N) row_start[i] += partials[i >> 10];
  if (i == 0) row_start[N] = E;
}

// bucket b covers nodes [b*128, (b+1)*128); its record segment base = row_start[b*128]
__global__ void k_bucket_base(const int* __restrict__ row_start, int* __restrict__ bucket_base,
                              int N, int NB) {
  int b = blockIdx.x * blockDim.x + threadIdx.x;
  if (b <= NB) bucket_base[b] = row_start[min(b << 7, N)];
}

// phase 1: append {dst, src} to the dst's bucket segment (sequential per bucket)
__global__ void k_scatter1(const int* __restrict__ src, const int* __restrict__ dst,
                           const int* __restrict__ bucket_base, int* __restrict__ bcur,
                           int2* __restrict__ tmp, int E) {
  int e = blockIdx.x * blockDim.x + threadIdx.x;
  if (e < E) {
    int d = dst[e], s = src[e];
    int b = d >> 7;
    int pos = atomicAdd(&bcur[b], 1);
    tmp[bucket_base[b] + pos] = make_int2(d, s);
  }
}

// phase 2: one block per bucket; reorder bucket records into final CSR slots.
// scattered writes span only the bucket's ~8KB window -> L2-local, full lines.
__global__ void k_scatter2(const int2* __restrict__ tmp, const int* __restrict__ bucket_base,
                           const int* __restrict__ row_start, int* __restrict__ recs,
                           int N) {
  __shared__ int lcur[128];
  int b = blockIdx.x;
  int t = threadIdx.x;
  int node0 = b << 7;
  if (t < 128) {
    int n = node0 + t;
    lcur[t] = (n < N) ? row_start[n] : 0;
  }
  __syncthreads();
  int beg = bucket_base[b], end = bucket_base[b + 1];
  for (int i = beg + t; i < end; i += 256) {
    int2 r = tmp[i];
    int slot = atomicAdd(&lcur[r.x & 127], 1);
    recs[slot] = r.y;
  }
}

// ---------------- GEMM via bf16-split MFMA ----------------
// Hb[N x 64] (bf16) = X[N x K] @ W[K x 64], fp32 in, bf16 out.
template <int K, int KC>
__global__ __launch_bounds__(256) void k_gemm_mfma(const float* __restrict__ X,
                                                   const float* __restrict__ W,
                                                   unsigned short* __restrict__ Hb, int N) {
  constexpr int KP = KC + 8;  // padded row (bf16 elems): 16B-aligned rows + bank break
  __shared__ unsigned short sAhi[64 * KP];
  __shared__ unsigned short sAlo[64 * KP];
  __shared__ unsigned short sBhi[64 * KP];  // [col][k] transposed
  __shared__ unsigned short sBlo[64 * KP];

  const int tid = threadIdx.x;
  const int row0 = blockIdx.x * 64;
  const int lane = tid & 63;
  const int wv = tid >> 6;
  const int r16 = lane & 15;
  const int half = lane >> 4;

  f32x4 acc[4];
#pragma unroll
  for (int f = 0; f < 4; ++f) acc[f] = (f32x4){0.f, 0.f, 0.f, 0.f};

  for (int ch = 0; ch < K / KC; ++ch) {
    const int kc0 = ch * KC;
    constexpr int KCV = KC / 4;
    for (int idx = tid; idx < 64 * KCV; idx += 256) {
      int r = idx / KCV, c4 = idx % KCV;
      int grow = row0 + r;
      float4 v;
      if (grow < N)
        v = *(const float4*)&X[(size_t)grow * K + kc0 + c4 * 4];
      else
        v = make_float4(0.f, 0.f, 0.f, 0.f);
      u16x4 hi, lo;
      float vv[4] = {v.x, v.y, v.z, v.w};
#pragma unroll
      for (int j = 0; j < 4; ++j) {
        unsigned short h = f2bf(vv[j]);
        hi[j] = h;
        lo[j] = f2bf(vv[j] - bf2f(h));
      }
      *(u16x4*)&sAhi[r * KP + c4 * 4] = hi;
      *(u16x4*)&sAlo[r * KP + c4 * 4] = lo;
    }
    for (int idx = tid; idx < KC * 64; idx += 256) {
      int k = idx >> 6, c = idx & 63;
      float wval = W[(size_t)(kc0 + k) * HD + c];
      unsigned short h = f2bf(wval);
      sBhi[c * KP + k] = h;
      sBlo[c * KP + k] = f2bf(wval - bf2f(h));
    }
    __syncthreads();
#pragma unroll
    for (int ks = 0; ks < KC; ks += 32) {
      const int ka = ks + half * 8;
      bf16x8 ahi = *(const bf16x8*)&sAhi[(wv * 16 + r16) * KP + ka];
      bf16x8 alo = *(const bf16x8*)&sAlo[(wv * 16 + r16) * KP + ka];
#pragma unroll
      for (int f = 0; f < 4; ++f) {
        bf16x8 bhi = *(const bf16x8*)&sBhi[(f * 16 + r16) * KP + ka];
        bf16x8 blo = *(const bf16x8*)&sBlo[(f * 16 + r16) * KP + ka];
        acc[f] = __builtin_amdgcn_mfma_f32_16x16x32_bf16(ahi, bhi, acc[f], 0, 0, 0);
        acc[f] = __builtin_amdgcn_mfma_f32_16x16x32_bf16(ahi, blo, acc[f], 0, 0, 0);
        acc[f] = __builtin_amdgcn_mfma_f32_16x16x32_bf16(alo, bhi, acc[f], 0, 0, 0);
      }
    }
    __syncthreads();
  }
  // store bf16: C layout col=lane&15, row=(lane>>4)*4+reg
  const int orow0 = row0 + wv * 16 + half * 4;
#pragma unroll
  for (int f = 0; f < 4; ++f) {
#pragma unroll
    for (int rg = 0; rg < 4; ++rg) {
      int orow = orow0 + rg;
      if (orow < N) Hb[(size_t)orow * HD + f * 16 + r16] = f2bf(acc[f][rg]);
    }
  }
}

// ---------------- Aggregation: bf16 gathers + f32 accumulate ----------------
// one wave per node, lane = channel; norm recomputed from L2-hot dinv
__global__ void k_agg(const unsigned short* __restrict__ Hb, const int* __restrict__ recs,
                      const int* __restrict__ row_start, const float* __restrict__ dinv,
                      const float* __restrict__ bias, float* __restrict__ out, int N,
                      int relu) {
  int lane = threadIdx.x & 63;
  int node = (blockIdx.x * blockDim.x + threadIdx.x) >> 6;
  if (node >= N) return;
  float di = dinv[node];
  float acc = bf2f(Hb[(size_t)node * HD + lane]) * (di * di);
  int beg = row_start[node], end = row_start[node + 1];
  int e = beg;
  for (; e + 4 <= end; e += 4) {
    int s0 = recs[e + 0], s1 = recs[e + 1], s2 = recs[e + 2], s3 = recs[e + 3];
    float n0 = dinv[s0], n1 = dinv[s1], n2 = dinv[s2], n3 = dinv[s3];
    float h0 = bf2f(Hb[(size_t)s0 * HD + lane]);
    float h1 = bf2f(Hb[(size_t)s1 * HD + lane]);
    float h2 = bf2f(Hb[(size_t)s2 * HD + lane]);
    float h3 = bf2f(Hb[(size_t)s3 * HD + lane]);
    acc = fmaf(h0, n0 * di, acc);
    acc = fmaf(h1, n1 * di, acc);
    acc = fmaf(h2, n2 * di, acc);
    acc = fmaf(h3, n3 * di, acc);
  }
  for (; e < end; ++e) {
    int s = recs[e];
    acc = fmaf(bf2f(Hb[(size_t)s * HD + lane]), dinv[s] * di, acc);
  }
  acc += bias[lane];
  if (relu) acc = fmaxf(acc, 0.f);
  out[(size_t)node * HD + lane] = acc;
}

// ---------------- zscore ----------------

__global__ void k_colstats(const float* __restrict__ H, float* __restrict__ stats, int N) {
  __shared__ float ss[256], sq[256];
  int t = threadIdx.x;
  int col = t & 63, grp = t >> 6;
  float s = 0.f, q = 0.f;
  for (int row = blockIdx.x * 4 + grp; row < N; row += gridDim.x * 4) {
    float v = H[(size_t)row * HD + col];
    s += v;
    q += v * v;
  }
  ss[t] = s;
  sq[t] = q;
  __syncthreads();
  if (t < 64) {
    s = ss[t] + ss[t + 64] + ss[t + 128] + ss[t + 192];
    q = sq[t] + sq[t + 64] + sq[t + 128] + sq[t + 192];
    atomicAdd(&stats[t], s);
    atomicAdd(&stats[64 + t], q);
  }
}

__global__ void k_normalize(float* __restrict__ H, const float* __restrict__ stats, int N) {
  int i = blockIdx.x * blockDim.x + threadIdx.x;
  int total = N * HD;
  if (i >= total) return;
  int col = i & 63;
  float sum = stats[col], sumsq = stats[64 + col];
  float mean = sum / (float)N;
  float var = (sumsq - sum * sum / (float)N) / (float)(N - 1);
  float r = rsqrtf(var);
  H[i] = (H[i] - mean) * r;
}

// ---------------- launch ----------------

extern "C" void kernel_launch(void* const* d_in, const int* in_sizes, int n_in,
                              void* d_out, int out_size, void* d_ws, size_t ws_size,
                              hipStream_t stream) {
  const int IN_DIM = 256;
  const float* X[2] = {(const float*)d_in[0], (const float*)d_in[2]};
  const int* EI[2] = {(const int*)d_in[1], (const int*)d_in[3]};
  const float* W1 = (const float*)d_in[4];
  const float* b1 = (const float*)d_in[5];
  const float* W2 = (const float*)d_in[6];
  const float* b2 = (const float*)d_in[7];
  const int N = in_sizes[0] / IN_DIM;
  const int E = in_sizes[1] / 2;
  const int NB = (N + 127) >> 7;  // nodes/bucket = 128

  // workspace carve-up (~60 MB)
  char* ws = (char*)d_ws;
  size_t off = 0;
  auto carve = [&](size_t bytes) -> char* {
    char* p = ws + off;
    off += (bytes + 255) & ~(size_t)255;
    return p;
  };
  unsigned short* Hb = (unsigned short*)carve((size_t)N * HD * 2);  // bf16 gemm out
  float* bufB = (float*)carve((size_t)N * HD * 4);                  // f32 agg out
  int2* tmp = (int2*)carve((size_t)E * 8);                          // bucketed {dst,src}
  int* recs = (int*)carve((size_t)E * 4);                           // final CSR src
  // contiguous zero region: deg[N] | bcur[NB] | stats[128]
  char* zero_base = carve(((size_t)N + NB + 128) * 4);
  int* deg = (int*)zero_base;
  int* bcur = deg + N;
  float* stats = (float*)(bcur + NB);
  int* row_start = (int*)carve((size_t)(N + 1) * 4);
  int* bucket_base = (int*)carve((size_t)(NB + 1) * 4);
  float* dinv = (float*)carve((size_t)N * 4);
  int* partials = (int*)carve(256 * 4);
  (void)ws_size; (void)n_in; (void)out_size;

  const int T = 256;
  const int gE = (E + T - 1) / T;
  const int gN = (N + T - 1) / T;
  const int nchunk = (N + 1023) / 1024;
  const int gWave4 = (N + 3) / 4;    // one wave per node, 4 waves/block
  const int gGemm = (N + 63) / 64;   // 64 rows per block
  const int gElem = (N * HD + T - 1) / T;
  const int gBB = (NB + 1 + T - 1) / T;

  for (int g = 0; g < 2; ++g) {
    const float* x = X[g];
    const int* src = EI[g];
    const int* dst = EI[g] + E;
    float* OUT = (float*)d_out + (size_t)g * N * HD;

    hipMemsetAsync(zero_base, 0, ((size_t)N + NB + 128) * 4, stream);
    k_deg<<<gE, T, 0, stream>>>(dst, deg, E);
    k_scan1<<<nchunk, T, 0, stream>>>(deg, row_start, partials, dinv, N);
    k_scan2<<<1, T, 0, stream>>>(partials, nchunk);
    k_scan3<<<gN, T, 0, stream>>>(row_start, partials, N, E);
    k_bucket_base<<<gBB, T, 0, stream>>>(row_start, bucket_base, N, NB);
    k_scatter1<<<gE, T, 0, stream>>>(src, dst, bucket_base, bcur, tmp, E);
    k_scatter2<<<NB, T, 0, stream>>>(tmp, bucket_base, row_start, recs, N);

    // layer 1: h = relu(agg(x @ W1) + b1)
    k_gemm_mfma<256, 128><<<gGemm, T, 0, stream>>>(x, W1, Hb, N);
    k_agg<<<gWave4, T, 0, stream>>>(Hb, recs, row_start, dinv, b1, bufB, N, 1);
    // layer 2: h = agg(h1 @ W2) + b2 -> straight into d_out segment
    k_gemm_mfma<64, 64><<<gGemm, T, 0, stream>>>(bufB, W2, Hb, N);
    k_agg<<<gWave4, T, 0, stream>>>(Hb, recs, row_start, dinv, b2, OUT, N, 0);

    // zscore in place on OUT
    k_colstats<<<512, T, 0, stream>>>(OUT, stats, N);
    k_normalize<<<gElem, T, 0, stream>>>(OUT, stats, N);
  }
}

// Round 5
// 776.168 us; speedup vs baseline: 1.8796x; 1.8796x over previous
//
#include <hip/hip_runtime.h>

#define HD 64        // hidden == out dim
#define CH 8192      // edges per bin1 block
#define BKT_SHIFT 10 // 1024 nodes per bucket
#define SRC_BITS 17  // N=100000 < 2^17 -> {dstlocal:10 | src:17} fits in 27 bits

typedef __attribute__((ext_vector_type(8))) short bf16x8;
typedef __attribute__((ext_vector_type(4))) float f32x4;
typedef __attribute__((ext_vector_type(4))) unsigned short u16x4;

__device__ inline unsigned short f2bf(float x) {
  unsigned u = __float_as_uint(x);
  unsigned r = u + 0x7FFF + ((u >> 16) & 1);
  return (unsigned short)(r >> 16);
}
__device__ inline float bf2f(unsigned short h) {
  return __uint_as_float(((unsigned)h) << 16);
}

// ---------------- binning pass 1: block-local bucket sort ----------------
// Each block: 8192 edges -> LDS histogram by bucket -> LDS reorder -> dump to
// its OWN contiguous tmp region (sequential full-line writes, no global
// cursor atomics). Also accumulates deg[] (folded k_deg).
__global__ __launch_bounds__(256) void k_bin1(const int* __restrict__ src,
                                              const int* __restrict__ dst,
                                              int* __restrict__ deg,
                                              int* __restrict__ tmp,
                                              int* __restrict__ counts,
                                              int* __restrict__ offsets,
                                              int NB, int NBLK, int E) {
  __shared__ int hist[128];
  __shared__ int pref[128];
  __shared__ int lofs[128];
  __shared__ int stage[CH];  // 32 KB
  const int blk = blockIdx.x;
  const int e0 = blk * CH;
  const int len = min(CH, E - e0);
  const int t = threadIdx.x;

  for (int i = t; i < 128; i += 256) hist[i] = 0;
  __syncthreads();
  for (int i = t; i < len; i += 256) {
    int d = dst[e0 + i];
    atomicAdd(&hist[d >> BKT_SHIFT], 1);
    atomicAdd(&deg[d], 1);
  }
  __syncthreads();
  // inclusive scan over 128 bins
  if (t < 128) pref[t] = hist[t];
  __syncthreads();
  for (int off = 1; off < 128; off <<= 1) {
    int v = 0;
    if (t < 128 && t >= off) v = pref[t - off];
    __syncthreads();
    if (t < 128) pref[t] += v;
    __syncthreads();
  }
  if (t < NB) {
    int ex = pref[t] - hist[t];
    lofs[t] = ex;
    counts[t * NBLK + blk] = hist[t];   // [bucket][block] for contiguous phase-2 reads
    offsets[t * NBLK + blk] = ex;
  }
  __syncthreads();
  // place into LDS stage, grouped by bucket
  for (int i = t; i < len; i += 256) {
    int d = dst[e0 + i], s = src[e0 + i];
    int b = d >> BKT_SHIFT;
    int slot = atomicAdd(&lofs[b], 1);
    stage[slot] = ((d & ((1 << BKT_SHIFT) - 1)) << SRC_BITS) | s;
  }
  __syncthreads();
  // dump sequential (int4)
  int nv = len >> 2;
  for (int i = t; i < nv; i += 256) ((int4*)(tmp + e0))[i] = ((const int4*)stage)[i];
  for (int i = (nv << 2) + t; i < len; i += 256) tmp[e0 + i] = stage[i];
}

// ---------------- binning pass 2: within-bucket CSR placement ----------------
// One block per bucket; LDS cursors for its 1024 nodes; writes confined to the
// bucket's ~64KB recs window -> lines assembled in local L2.
__global__ __launch_bounds__(256) void k_bin2(const int* __restrict__ tmp,
                                              const int* __restrict__ counts,
                                              const int* __restrict__ offsets,
                                              const int* __restrict__ row_start,
                                              int* __restrict__ recs, int N, int NBLK) {
  __shared__ int lcur[1 << BKT_SHIFT];
  __shared__ int scnt[512], soff[512];
  const int b = blockIdx.x;
  const int t = threadIdx.x;
  const int node0 = b << BKT_SHIFT;
  for (int i = t; i < (1 << BKT_SHIFT); i += 256) {
    int n = node0 + i;
    lcur[i] = (n < N) ? row_start[n] : 0;
  }
  for (int i = t; i < NBLK; i += 256) {
    scnt[i] = counts[b * NBLK + i];
    soff[i] = offsets[b * NBLK + i];
  }
  __syncthreads();
  const int lane = t & 63, w = t >> 6;
  for (int blk = w; blk < NBLK; blk += 4) {
    int cnt = scnt[blk];
    const int* p = tmp + blk * CH + soff[blk];
    for (int j = lane; j < cnt; j += 64) {
      int rec = p[j];
      int d = rec >> SRC_BITS;
      int s = rec & ((1 << SRC_BITS) - 1);
      int slot = atomicAdd(&lcur[d], 1);
      recs[slot] = s;
    }
  }
}

// ---------------- prefix scan for row_start (+ dinv) ----------------

__global__ void k_scan1(const int* __restrict__ deg, int* __restrict__ row_start,
                        int* __restrict__ partials, float* __restrict__ dinv, int N) {
  __shared__ int sh[256];
  int t = threadIdx.x;
  int base = blockIdx.x * 1024 + t * 4;
  int v0 = 0, v1 = 0, v2 = 0, v3 = 0;
  if (base + 0 < N) v0 = deg[base + 0];
  if (base + 1 < N) v1 = deg[base + 1];
  if (base + 2 < N) v2 = deg[base + 2];
  if (base + 3 < N) v3 = deg[base + 3];
  if (base + 0 < N) dinv[base + 0] = rsqrtf((float)v0 + 1.0f);
  if (base + 1 < N) dinv[base + 1] = rsqrtf((float)v1 + 1.0f);
  if (base + 2 < N) dinv[base + 2] = rsqrtf((float)v2 + 1.0f);
  if (base + 3 < N) dinv[base + 3] = rsqrtf((float)v3 + 1.0f);
  int tsum = v0 + v1 + v2 + v3;
  sh[t] = tsum;
  __syncthreads();
  for (int off = 1; off < 256; off <<= 1) {
    int x = (t >= off) ? sh[t - off] : 0;
    __syncthreads();
    sh[t] += x;
    __syncthreads();
  }
  int excl = sh[t] - tsum;
  if (t == 255) partials[blockIdx.x] = sh[255];
  if (base + 0 < N) row_start[base + 0] = excl;
  if (base + 1 < N) row_start[base + 1] = excl + v0;
  if (base + 2 < N) row_start[base + 2] = excl + v0 + v1;
  if (base + 3 < N) row_start[base + 3] = excl + v0 + v1 + v2;
}

__global__ void k_scan2(int* partials, int nb) {  // nb <= 256
  __shared__ int sh[256];
  int t = threadIdx.x;
  int v = (t < nb) ? partials[t] : 0;
  sh[t] = v;
  __syncthreads();
  for (int off = 1; off < 256; off <<= 1) {
    int x = (t >= off) ? sh[t - off] : 0;
    __syncthreads();
    sh[t] += x;
    __syncthreads();
  }
  if (t < nb) partials[t] = sh[t] - v;  // exclusive
}

__global__ void k_scan3(int* __restrict__ row_start, const int* __restrict__ partials,
                        int N, int E) {
  int i = blockIdx.x * blockDim.x + threadIdx.x;
  if (i < N) row_start[i] += partials[i >> 10];
  if (i == 0) row_start[N] = E;
}

// ---------------- GEMM via bf16-split MFMA ----------------
template <int K, int KC>
__global__ __launch_bounds__(256) void k_gemm_mfma(const float* __restrict__ X,
                                                   const float* __restrict__ W,
                                                   unsigned short* __restrict__ Hb, int N) {
  constexpr int KP = KC + 8;
  __shared__ unsigned short sAhi[64 * KP];
  __shared__ unsigned short sAlo[64 * KP];
  __shared__ unsigned short sBhi[64 * KP];
  __shared__ unsigned short sBlo[64 * KP];

  const int tid = threadIdx.x;
  const int row0 = blockIdx.x * 64;
  const int lane = tid & 63;
  const int wv = tid >> 6;
  const int r16 = lane & 15;
  const int half = lane >> 4;

  f32x4 acc[4];
#pragma unroll
  for (int f = 0; f < 4; ++f) acc[f] = (f32x4){0.f, 0.f, 0.f, 0.f};

  for (int ch = 0; ch < K / KC; ++ch) {
    const int kc0 = ch * KC;
    constexpr int KCV = KC / 4;
    for (int idx = tid; idx < 64 * KCV; idx += 256) {
      int r = idx / KCV, c4 = idx % KCV;
      int grow = row0 + r;
      float4 v;
      if (grow < N)
        v = *(const float4*)&X[(size_t)grow * K + kc0 + c4 * 4];
      else
        v = make_float4(0.f, 0.f, 0.f, 0.f);
      u16x4 hi, lo;
      float vv[4] = {v.x, v.y, v.z, v.w};
#pragma unroll
      for (int j = 0; j < 4; ++j) {
        unsigned short h = f2bf(vv[j]);
        hi[j] = h;
        lo[j] = f2bf(vv[j] - bf2f(h));
      }
      *(u16x4*)&sAhi[r * KP + c4 * 4] = hi;
      *(u16x4*)&sAlo[r * KP + c4 * 4] = lo;
    }
    for (int idx = tid; idx < KC * 64; idx += 256) {
      int k = idx >> 6, c = idx & 63;
      float wval = W[(size_t)(kc0 + k) * HD + c];
      unsigned short h = f2bf(wval);
      sBhi[c * KP + k] = h;
      sBlo[c * KP + k] = f2bf(wval - bf2f(h));
    }
    __syncthreads();
#pragma unroll
    for (int ks = 0; ks < KC; ks += 32) {
      const int ka = ks + half * 8;
      bf16x8 ahi = *(const bf16x8*)&sAhi[(wv * 16 + r16) * KP + ka];
      bf16x8 alo = *(const bf16x8*)&sAlo[(wv * 16 + r16) * KP + ka];
#pragma unroll
      for (int f = 0; f < 4; ++f) {
        bf16x8 bhi = *(const bf16x8*)&sBhi[(f * 16 + r16) * KP + ka];
        bf16x8 blo = *(const bf16x8*)&sBlo[(f * 16 + r16) * KP + ka];
        acc[f] = __builtin_amdgcn_mfma_f32_16x16x32_bf16(ahi, bhi, acc[f], 0, 0, 0);
        acc[f] = __builtin_amdgcn_mfma_f32_16x16x32_bf16(ahi, blo, acc[f], 0, 0, 0);
        acc[f] = __builtin_amdgcn_mfma_f32_16x16x32_bf16(alo, bhi, acc[f], 0, 0, 0);
      }
    }
    __syncthreads();
  }
  const int orow0 = row0 + wv * 16 + half * 4;
#pragma unroll
  for (int f = 0; f < 4; ++f) {
#pragma unroll
    for (int rg = 0; rg < 4; ++rg) {
      int orow = orow0 + rg;
      if (orow < N) Hb[(size_t)orow * HD + f * 16 + r16] = f2bf(acc[f][rg]);
    }
  }
}

// ---------------- Aggregation: bf16 gathers + f32 accumulate ----------------
__global__ void k_agg(const unsigned short* __restrict__ Hb, const int* __restrict__ recs,
                      const int* __restrict__ row_start, const float* __restrict__ dinv,
                      const float* __restrict__ bias, float* __restrict__ out, int N,
                      int relu) {
  int lane = threadIdx.x & 63;
  int node = (blockIdx.x * blockDim.x + threadIdx.x) >> 6;
  if (node >= N) return;
  float di = dinv[node];
  float acc = bf2f(Hb[(size_t)node * HD + lane]) * (di * di);
  int beg = row_start[node], end = row_start[node + 1];
  int e = beg;
  for (; e + 4 <= end; e += 4) {
    int s0 = recs[e + 0], s1 = recs[e + 1], s2 = recs[e + 2], s3 = recs[e + 3];
    float n0 = dinv[s0], n1 = dinv[s1], n2 = dinv[s2], n3 = dinv[s3];
    float h0 = bf2f(Hb[(size_t)s0 * HD + lane]);
    float h1 = bf2f(Hb[(size_t)s1 * HD + lane]);
    float h2 = bf2f(Hb[(size_t)s2 * HD + lane]);
    float h3 = bf2f(Hb[(size_t)s3 * HD + lane]);
    acc = fmaf(h0, n0 * di, acc);
    acc = fmaf(h1, n1 * di, acc);
    acc = fmaf(h2, n2 * di, acc);
    acc = fmaf(h3, n3 * di, acc);
  }
  for (; e < end; ++e) {
    int s = recs[e];
    acc = fmaf(bf2f(Hb[(size_t)s * HD + lane]), dinv[s] * di, acc);
  }
  acc += bias[lane];
  if (relu) acc = fmaxf(acc, 0.f);
  out[(size_t)node * HD + lane] = acc;
}

// ---------------- zscore ----------------

__global__ void k_colstats(const float* __restrict__ H, float* __restrict__ stats, int N) {
  __shared__ float ss[256], sq[256];
  int t = threadIdx.x;
  int col = t & 63, grp = t >> 6;
  float s = 0.f, q = 0.f;
  for (int row = blockIdx.x * 4 + grp; row < N; row += gridDim.x * 4) {
    float v = H[(size_t)row * HD + col];
    s += v;
    q += v * v;
  }
  ss[t] = s;
  sq[t] = q;
  __syncthreads();
  if (t < 64) {
    s = ss[t] + ss[t + 64] + ss[t + 128] + ss[t + 192];
    q = sq[t] + sq[t + 64] + sq[t + 128] + sq[t + 192];
    atomicAdd(&stats[t], s);
    atomicAdd(&stats[64 + t], q);
  }
}

__global__ void k_normalize(float* __restrict__ H, const float* __restrict__ stats, int N) {
  int i = blockIdx.x * blockDim.x + threadIdx.x;
  int total = N * HD;
  if (i >= total) return;
  int col = i & 63;
  float sum = stats[col], sumsq = stats[64 + col];
  float mean = sum / (float)N;
  float var = (sumsq - sum * sum / (float)N) / (float)(N - 1);
  float r = rsqrtf(var);
  H[i] = (H[i] - mean) * r;
}

// ---------------- launch ----------------

extern "C" void kernel_launch(void* const* d_in, const int* in_sizes, int n_in,
                              void* d_out, int out_size, void* d_ws, size_t ws_size,
                              hipStream_t stream) {
  const int IN_DIM = 256;
  const float* X[2] = {(const float*)d_in[0], (const float*)d_in[2]};
  const int* EI[2] = {(const int*)d_in[1], (const int*)d_in[3]};
  const float* W1 = (const float*)d_in[4];
  const float* b1 = (const float*)d_in[5];
  const float* W2 = (const float*)d_in[6];
  const float* b2 = (const float*)d_in[7];
  const int N = in_sizes[0] / IN_DIM;
  const int E = in_sizes[1] / 2;
  const int NB = (N + (1 << BKT_SHIFT) - 1) >> BKT_SHIFT;  // buckets (98)
  const int NBLK = (E + CH - 1) / CH;                      // bin1 blocks (196)

  char* ws = (char*)d_ws;
  size_t off = 0;
  auto carve = [&](size_t bytes) -> char* {
    char* p = ws + off;
    off += (bytes + 255) & ~(size_t)255;
    return p;
  };
  unsigned short* Hb = (unsigned short*)carve((size_t)N * HD * 2);
  float* bufB = (float*)carve((size_t)N * HD * 4);
  int* tmp = (int*)carve((size_t)NBLK * CH * 4);  // bucket-grouped packed edges
  int* recs = (int*)carve((size_t)E * 4);         // final CSR src
  // contiguous zero region: deg[N] | stats[128]
  char* zero_base = carve(((size_t)N + 128) * 4);
  int* deg = (int*)zero_base;
  float* stats = (float*)(deg + N);
  int* row_start = (int*)carve((size_t)(N + 1) * 4);
  float* dinv = (float*)carve((size_t)N * 4);
  int* partials = (int*)carve(256 * 4);
  int* counts = (int*)carve((size_t)NB * NBLK * 4);
  int* offsets = (int*)carve((size_t)NB * NBLK * 4);
  (void)ws_size; (void)n_in; (void)out_size;

  const int T = 256;
  const int gN = (N + T - 1) / T;
  const int nchunk = (N + 1023) / 1024;
  const int gWave4 = (N + 3) / 4;
  const int gGemm = (N + 63) / 64;
  const int gElem = (N * HD + T - 1) / T;

  for (int g = 0; g < 2; ++g) {
    const float* x = X[g];
    const int* src = EI[g];
    const int* dst = EI[g] + E;
    float* OUT = (float*)d_out + (size_t)g * N * HD;

    hipMemsetAsync(zero_base, 0, ((size_t)N + 128) * 4, stream);
    k_bin1<<<NBLK, T, 0, stream>>>(src, dst, deg, tmp, counts, offsets, NB, NBLK, E);
    k_scan1<<<nchunk, T, 0, stream>>>(deg, row_start, partials, dinv, N);
    k_scan2<<<1, T, 0, stream>>>(partials, nchunk);
    k_scan3<<<gN, T, 0, stream>>>(row_start, partials, N, E);
    k_bin2<<<NB, T, 0, stream>>>(tmp, counts, offsets, row_start, recs, N, NBLK);

    // layer 1: h = relu(agg(x @ W1) + b1)
    k_gemm_mfma<256, 128><<<gGemm, T, 0, stream>>>(x, W1, Hb, N);
    k_agg<<<gWave4, T, 0, stream>>>(Hb, recs, row_start, dinv, b1, bufB, N, 1);
    // layer 2: h = agg(h1 @ W2) + b2 -> straight into d_out segment
    k_gemm_mfma<64, 64><<<gGemm, T, 0, stream>>>(bufB, W2, Hb, N);
    k_agg<<<gWave4, T, 0, stream>>>(Hb, recs, row_start, dinv, b2, OUT, N, 0);

    // zscore in place on OUT
    k_colstats<<<512, T, 0, stream>>>(OUT, stats, N);
    k_normalize<<<gElem, T, 0, stream>>>(OUT, stats, N);
  }
}

// Round 6
// 741.804 us; speedup vs baseline: 1.9666x; 1.0463x over previous
//
#include <hip/hip_runtime.h>

#define HD 64        // hidden == out dim
#define CH 8192      // edges per bin1 block
#define BKT_SHIFT 10 // 1024 nodes per bucket
#define SRC_BITS 17  // N=100000 < 2^17 -> {dstlocal:10 | src:17} fits in 27 bits

typedef __attribute__((ext_vector_type(8))) short bf16x8;
typedef __attribute__((ext_vector_type(4))) float f32x4;

__device__ inline unsigned short f2bf(float x) {
  unsigned u = __float_as_uint(x);
  unsigned r = u + 0x7FFF + ((u >> 16) & 1);
  return (unsigned short)(r >> 16);
}
__device__ inline float bf2f(unsigned short h) {
  return __uint_as_float(((unsigned)h) << 16);
}

// ---------------- binning pass 1: block-local bucket sort ----------------
__global__ __launch_bounds__(256) void k_bin1(const int* __restrict__ src,
                                              const int* __restrict__ dst,
                                              int* __restrict__ deg,
                                              int* __restrict__ tmp,
                                              int* __restrict__ counts,
                                              int* __restrict__ offsets,
                                              int NB, int NBLK, int E) {
  __shared__ int hist[128];
  __shared__ int pref[128];
  __shared__ int lofs[128];
  __shared__ int stage[CH];  // 32 KB
  const int blk = blockIdx.x;
  const int e0 = blk * CH;
  const int len = min(CH, E - e0);
  const int t = threadIdx.x;

  for (int i = t; i < 128; i += 256) hist[i] = 0;
  __syncthreads();
  for (int i = t; i < len; i += 256) {
    int d = dst[e0 + i];
    atomicAdd(&hist[d >> BKT_SHIFT], 1);
    atomicAdd(&deg[d], 1);
  }
  __syncthreads();
  if (t < 128) pref[t] = hist[t];
  __syncthreads();
  for (int off = 1; off < 128; off <<= 1) {
    int v = 0;
    if (t < 128 && t >= off) v = pref[t - off];
    __syncthreads();
    if (t < 128) pref[t] += v;
    __syncthreads();
  }
  if (t < NB) {
    int ex = pref[t] - hist[t];
    lofs[t] = ex;
    counts[t * NBLK + blk] = hist[t];
    offsets[t * NBLK + blk] = ex;
  }
  __syncthreads();
  for (int i = t; i < len; i += 256) {
    int d = dst[e0 + i], s = src[e0 + i];
    int b = d >> BKT_SHIFT;
    int slot = atomicAdd(&lofs[b], 1);
    stage[slot] = ((d & ((1 << BKT_SHIFT) - 1)) << SRC_BITS) | s;
  }
  __syncthreads();
  int nv = len >> 2;
  for (int i = t; i < nv; i += 256) ((int4*)(tmp + e0))[i] = ((const int4*)stage)[i];
  for (int i = (nv << 2) + t; i < len; i += 256) tmp[e0 + i] = stage[i];
}

// ---------------- binning pass 2: within-bucket CSR placement ----------------
__global__ __launch_bounds__(256) void k_bin2(const int* __restrict__ tmp,
                                              const int* __restrict__ counts,
                                              const int* __restrict__ offsets,
                                              const int* __restrict__ row_start,
                                              int* __restrict__ recs, int N, int NBLK) {
  __shared__ int lcur[1 << BKT_SHIFT];
  __shared__ int scnt[512], soff[512];
  const int b = blockIdx.x;
  const int t = threadIdx.x;
  const int node0 = b << BKT_SHIFT;
  for (int i = t; i < (1 << BKT_SHIFT); i += 256) {
    int n = node0 + i;
    lcur[i] = (n < N) ? row_start[n] : 0;
  }
  for (int i = t; i < NBLK; i += 256) {
    scnt[i] = counts[b * NBLK + i];
    soff[i] = offsets[b * NBLK + i];
  }
  __syncthreads();
  const int lane = t & 63, w = t >> 6;
  for (int blk = w; blk < NBLK; blk += 4) {
    int cnt = scnt[blk];
    const int* p = tmp + blk * CH + soff[blk];
    for (int j = lane; j < cnt; j += 64) {
      int rec = p[j];
      int d = rec >> SRC_BITS;
      int s = rec & ((1 << SRC_BITS) - 1);
      int slot = atomicAdd(&lcur[d], 1);
      recs[slot] = s;
    }
  }
}

// ---------------- prefix scan for row_start (+ dinv) ----------------

__global__ void k_scan1(const int* __restrict__ deg, int* __restrict__ row_start,
                        int* __restrict__ partials, float* __restrict__ dinv, int N) {
  __shared__ int sh[256];
  int t = threadIdx.x;
  int base = blockIdx.x * 1024 + t * 4;
  int v0 = 0, v1 = 0, v2 = 0, v3 = 0;
  if (base + 0 < N) v0 = deg[base + 0];
  if (base + 1 < N) v1 = deg[base + 1];
  if (base + 2 < N) v2 = deg[base + 2];
  if (base + 3 < N) v3 = deg[base + 3];
  if (base + 0 < N) dinv[base + 0] = rsqrtf((float)v0 + 1.0f);
  if (base + 1 < N) dinv[base + 1] = rsqrtf((float)v1 + 1.0f);
  if (base + 2 < N) dinv[base + 2] = rsqrtf((float)v2 + 1.0f);
  if (base + 3 < N) dinv[base + 3] = rsqrtf((float)v3 + 1.0f);
  int tsum = v0 + v1 + v2 + v3;
  sh[t] = tsum;
  __syncthreads();
  for (int off = 1; off < 256; off <<= 1) {
    int x = (t >= off) ? sh[t - off] : 0;
    __syncthreads();
    sh[t] += x;
    __syncthreads();
  }
  int excl = sh[t] - tsum;
  if (t == 255) partials[blockIdx.x] = sh[255];
  if (base + 0 < N) row_start[base + 0] = excl;
  if (base + 1 < N) row_start[base + 1] = excl + v0;
  if (base + 2 < N) row_start[base + 2] = excl + v0 + v1;
  if (base + 3 < N) row_start[base + 3] = excl + v0 + v1 + v2;
}

__global__ void k_scan2(int* partials, int nb) {  // nb <= 256
  __shared__ int sh[256];
  int t = threadIdx.x;
  int v = (t < nb) ? partials[t] : 0;
  sh[t] = v;
  __syncthreads();
  for (int off = 1; off < 256; off <<= 1) {
    int x = (t >= off) ? sh[t - off] : 0;
    __syncthreads();
    sh[t] += x;
    __syncthreads();
  }
  if (t < nb) partials[t] = sh[t] - v;  // exclusive
}

__global__ void k_scan3(int* __restrict__ row_start, const int* __restrict__ partials,
                        int N, int E) {
  int i = blockIdx.x * blockDim.x + threadIdx.x;
  if (i < N) row_start[i] += partials[i >> 10];
  if (i == 0) row_start[N] = E;
}

// ---------------- GEMM via MFMA, A direct from global ----------------
// Hb[N x 64] (bf16) = X[N x K] @ W[K x 64].
// A fragments loaded straight from global per lane (f32: convert to hi/lo in
// regs, 3 MFMAs; bf16 input: exact, 2 MFMAs). B staged ONCE in LDS as
// pre-swizzled fragments: frag (ks,f) at [(ks*4+f)*64 + lane]*8 -> every
// ds_read_b128 is stride-1 across the wave (conflict-free). No barriers in
// the K loop.
template <int K, int A_BF16>
__global__ __launch_bounds__(256) void k_gemm(const void* __restrict__ Xv,
                                              const float* __restrict__ W,
                                              unsigned short* __restrict__ Hb, int N) {
  constexpr int NKS = K / 32;
  __shared__ unsigned short sBhi[NKS * 4 * 64 * 8];
  __shared__ unsigned short sBlo[NKS * 4 * 64 * 8];
  const int tid = threadIdx.x;

  // stage B fragments (one time): W[k][c], k=idx>>6, c=idx&63
  for (int idx = tid; idx < K * 64; idx += 256) {
    int k = idx >> 6, c = idx & 63;
    float wval = W[idx];
    int ks = k >> 5, r = k & 31, h2 = r >> 3, j = r & 7;
    int f = c >> 4, r16c = c & 15;
    int pos = (((ks * 4 + f) * 64) + h2 * 16 + r16c) * 8 + j;
    unsigned short hi = f2bf(wval);
    sBhi[pos] = hi;
    sBlo[pos] = f2bf(wval - bf2f(hi));
  }
  __syncthreads();

  const int lane = tid & 63;
  const int wv = tid >> 6;
  const int r16 = lane & 15;
  const int half = lane >> 4;
  const int row = blockIdx.x * 64 + wv * 16 + r16;

  f32x4 acc[4];
#pragma unroll
  for (int f = 0; f < 4; ++f) acc[f] = (f32x4){0.f, 0.f, 0.f, 0.f};

#pragma unroll
  for (int ks = 0; ks < NKS; ++ks) {
    bf16x8 ahi, alo;
    if constexpr (A_BF16) {
      union { uint4 u; bf16x8 v; } au;
      au.u = make_uint4(0, 0, 0, 0);
      if (row < N)
        au.u = *(const uint4*)((const unsigned short*)Xv + (size_t)row * K + ks * 32 + half * 8);
      ahi = au.v;
    } else {
      float4 v0 = make_float4(0.f, 0.f, 0.f, 0.f), v1 = v0;
      if (row < N) {
        const float* xp = (const float*)Xv + (size_t)row * K + ks * 32 + half * 8;
        v0 = *(const float4*)xp;
        v1 = *(const float4*)(xp + 4);
      }
      float vv[8] = {v0.x, v0.y, v0.z, v0.w, v1.x, v1.y, v1.z, v1.w};
#pragma unroll
      for (int j = 0; j < 8; ++j) {
        unsigned short h = f2bf(vv[j]);
        ahi[j] = (short)h;
        alo[j] = (short)f2bf(vv[j] - bf2f(h));
      }
    }
#pragma unroll
    for (int f = 0; f < 4; ++f) {
      bf16x8 bh = *(const bf16x8*)&sBhi[(((ks * 4 + f) * 64) + lane) * 8];
      bf16x8 bl = *(const bf16x8*)&sBlo[(((ks * 4 + f) * 64) + lane) * 8];
      acc[f] = __builtin_amdgcn_mfma_f32_16x16x32_bf16(ahi, bh, acc[f], 0, 0, 0);
      acc[f] = __builtin_amdgcn_mfma_f32_16x16x32_bf16(ahi, bl, acc[f], 0, 0, 0);
      if constexpr (!A_BF16)
        acc[f] = __builtin_amdgcn_mfma_f32_16x16x32_bf16(alo, bh, acc[f], 0, 0, 0);
    }
  }

  // store bf16: C layout col=lane&15, row=(lane>>4)*4+reg
  const int orow0 = blockIdx.x * 64 + wv * 16 + half * 4;
#pragma unroll
  for (int f = 0; f < 4; ++f) {
#pragma unroll
    for (int rg = 0; rg < 4; ++rg) {
      int orow = orow0 + rg;
      if (orow < N) Hb[(size_t)orow * HD + f * 16 + r16] = f2bf(acc[f][rg]);
    }
  }
}

// ---------------- Aggregation: bf16 gathers + f32 accumulate ----------------
// one wave per node, lane = channel; OUTBF16 selects output dtype
template <int OUTBF16>
__global__ void k_agg(const unsigned short* __restrict__ Hb, const int* __restrict__ recs,
                      const int* __restrict__ row_start, const float* __restrict__ dinv,
                      const float* __restrict__ bias, void* __restrict__ outv, int N,
                      int relu) {
  int lane = threadIdx.x & 63;
  int node = (blockIdx.x * blockDim.x + threadIdx.x) >> 6;
  if (node >= N) return;
  float di = dinv[node];
  float acc = bf2f(Hb[(size_t)node * HD + lane]) * (di * di);
  int beg = row_start[node], end = row_start[node + 1];
  int e = beg;
  for (; e + 4 <= end; e += 4) {
    int s0 = recs[e + 0], s1 = recs[e + 1], s2 = recs[e + 2], s3 = recs[e + 3];
    float n0 = dinv[s0], n1 = dinv[s1], n2 = dinv[s2], n3 = dinv[s3];
    float h0 = bf2f(Hb[(size_t)s0 * HD + lane]);
    float h1 = bf2f(Hb[(size_t)s1 * HD + lane]);
    float h2 = bf2f(Hb[(size_t)s2 * HD + lane]);
    float h3 = bf2f(Hb[(size_t)s3 * HD + lane]);
    acc = fmaf(h0, n0 * di, acc);
    acc = fmaf(h1, n1 * di, acc);
    acc = fmaf(h2, n2 * di, acc);
    acc = fmaf(h3, n3 * di, acc);
  }
  for (; e < end; ++e) {
    int s = recs[e];
    acc = fmaf(bf2f(Hb[(size_t)s * HD + lane]), dinv[s] * di, acc);
  }
  acc += bias[lane];
  if (relu) acc = fmaxf(acc, 0.f);
  if (OUTBF16)
    ((unsigned short*)outv)[(size_t)node * HD + lane] = f2bf(acc);
  else
    ((float*)outv)[(size_t)node * HD + lane] = acc;
}

// ---------------- zscore ----------------

__global__ void k_colstats(const float* __restrict__ H, float* __restrict__ stats, int N) {
  __shared__ float ss[256], sq[256];
  int t = threadIdx.x;
  int col = t & 63, grp = t >> 6;
  float s = 0.f, q = 0.f;
  for (int row = blockIdx.x * 4 + grp; row < N; row += gridDim.x * 4) {
    float v = H[(size_t)row * HD + col];
    s += v;
    q += v * v;
  }
  ss[t] = s;
  sq[t] = q;
  __syncthreads();
  if (t < 64) {
    s = ss[t] + ss[t + 64] + ss[t + 128] + ss[t + 192];
    q = sq[t] + sq[t + 64] + sq[t + 128] + sq[t + 192];
    atomicAdd(&stats[t], s);
    atomicAdd(&stats[64 + t], q);
  }
}

__global__ void k_normalize(float* __restrict__ H, const float* __restrict__ stats, int N) {
  int i = blockIdx.x * blockDim.x + threadIdx.x;
  int total = N * HD;
  if (i >= total) return;
  int col = i & 63;
  float sum = stats[col], sumsq = stats[64 + col];
  float mean = sum / (float)N;
  float var = (sumsq - sum * sum / (float)N) / (float)(N - 1);
  float r = rsqrtf(var);
  H[i] = (H[i] - mean) * r;
}

// ---------------- launch ----------------

extern "C" void kernel_launch(void* const* d_in, const int* in_sizes, int n_in,
                              void* d_out, int out_size, void* d_ws, size_t ws_size,
                              hipStream_t stream) {
  const int IN_DIM = 256;
  const float* X[2] = {(const float*)d_in[0], (const float*)d_in[2]};
  const int* EI[2] = {(const int*)d_in[1], (const int*)d_in[3]};
  const float* W1 = (const float*)d_in[4];
  const float* b1 = (const float*)d_in[5];
  const float* W2 = (const float*)d_in[6];
  const float* b2 = (const float*)d_in[7];
  const int N = in_sizes[0] / IN_DIM;
  const int E = in_sizes[1] / 2;
  const int NB = (N + (1 << BKT_SHIFT) - 1) >> BKT_SHIFT;  // buckets (98)
  const int NBLK = (E + CH - 1) / CH;                      // bin1 blocks (196)

  char* ws = (char*)d_ws;
  size_t off = 0;
  auto carve = [&](size_t bytes) -> char* {
    char* p = ws + off;
    off += (bytes + 255) & ~(size_t)255;
    return p;
  };
  unsigned short* Hb = (unsigned short*)carve((size_t)N * HD * 2);      // gemm out (bf16)
  unsigned short* bufAgg = (unsigned short*)carve((size_t)N * HD * 2);  // agg1 out (bf16)
  int* tmp = (int*)carve((size_t)NBLK * CH * 4);
  int* recs = (int*)carve((size_t)E * 4);
  char* zero_base = carve(((size_t)N + 128) * 4);  // deg[N] | stats[128]
  int* deg = (int*)zero_base;
  float* stats = (float*)(deg + N);
  int* row_start = (int*)carve((size_t)(N + 1) * 4);
  float* dinv = (float*)carve((size_t)N * 4);
  int* partials = (int*)carve(256 * 4);
  int* counts = (int*)carve((size_t)NB * NBLK * 4);
  int* offsets = (int*)carve((size_t)NB * NBLK * 4);
  (void)ws_size; (void)n_in; (void)out_size;

  const int T = 256;
  const int gN = (N + T - 1) / T;
  const int nchunk = (N + 1023) / 1024;
  const int gWave4 = (N + 3) / 4;
  const int gGemm = (N + 63) / 64;
  const int gElem = (N * HD + T - 1) / T;

  for (int g = 0; g < 2; ++g) {
    const float* x = X[g];
    const int* src = EI[g];
    const int* dst = EI[g] + E;
    float* OUT = (float*)d_out + (size_t)g * N * HD;

    hipMemsetAsync(zero_base, 0, ((size_t)N + 128) * 4, stream);
    k_bin1<<<NBLK, T, 0, stream>>>(src, dst, deg, tmp, counts, offsets, NB, NBLK, E);
    k_scan1<<<nchunk, T, 0, stream>>>(deg, row_start, partials, dinv, N);
    k_scan2<<<1, T, 0, stream>>>(partials, nchunk);
    k_scan3<<<gN, T, 0, stream>>>(row_start, partials, N, E);
    k_bin2<<<NB, T, 0, stream>>>(tmp, counts, offsets, row_start, recs, N, NBLK);

    // layer 1: h = relu(agg(x @ W1) + b1)  [agg out bf16]
    k_gemm<256, 0><<<gGemm, T, 0, stream>>>(x, W1, Hb, N);
    k_agg<1><<<gWave4, T, 0, stream>>>(Hb, recs, row_start, dinv, b1, bufAgg, N, 1);
    // layer 2: h = agg(h1 @ W2) + b2 -> f32 straight into d_out segment
    k_gemm<64, 1><<<gGemm, T, 0, stream>>>(bufAgg, W2, Hb, N);
    k_agg<0><<<gWave4, T, 0, stream>>>(Hb, recs, row_start, dinv, b2, OUT, N, 0);

    // zscore in place on OUT
    k_colstats<<<512, T, 0, stream>>>(OUT, stats, N);
    k_normalize<<<gElem, T, 0, stream>>>(OUT, stats, N);
  }
}